// Round 8
// baseline (312.488 us; speedup 1.0000x reference)
//
#include <hip/hip_runtime.h>

// Problem constants
#define BATCH 2
#define SLEN 2048
#define DMODEL 1024
#define NHEAD 16
#define HDIM 64
#define MROWS (BATCH * SLEN)   // 4096

typedef __attribute__((ext_vector_type(8))) short bf16x8;
typedef __attribute__((ext_vector_type(4))) short bf16x4;
typedef __attribute__((ext_vector_type(4))) float f32x4;

__device__ inline short f2bf(float x) {
    union { float f; unsigned u; } v; v.f = x;
    unsigned r = (v.u + 0x7FFFu + ((v.u >> 16) & 1u)) >> 16;
    return (short)r;
}
__device__ inline float bf2f(short h) {
    union { unsigned u; float f; } v; v.u = ((unsigned)(unsigned short)h) << 16;
    return v.f;
}
// returns {hi, lo} bf16 split of x: x ~= hi + lo
__device__ inline short2 split2(float x) {
    short hi = f2bf(x);
    short lo = f2bf(x - bf2f(hi));
    return make_short2(hi, lo);
}
__device__ inline unsigned fbits(float x) {
    union { float f; unsigned u; } v; v.f = x; return v.u;
}

// ---------------- prep: split fp32 -> (hi, lo) bf16, same layout
__global__ __launch_bounds__(256) void split_2d(
    const float* __restrict__ in, short* __restrict__ hi, short* __restrict__ lo, int n4)
{
    int i = blockIdx.x * 256 + threadIdx.x;
    if (i >= n4) return;
    float4 f = ((const float4*)in)[i];
    short2 a = split2(f.x), b = split2(f.y), c = split2(f.z), d = split2(f.w);
    bf16x4 h, l;
    h[0] = a.x; h[1] = b.x; h[2] = c.x; h[3] = d.x;
    l[0] = a.y; l[1] = b.y; l[2] = c.y; l[3] = d.y;
    ((bf16x4*)hi)[i] = h;
    ((bf16x4*)lo)[i] = l;
}

// ---------------- prep: split + transpose W[K][N] -> WT_hi/lo [N][K]
__global__ __launch_bounds__(256) void split_transpose(
    const float* __restrict__ in, short* __restrict__ hiT, short* __restrict__ loT,
    int K, int N)
{
    __shared__ float T[64][68];
    const int tid = threadIdx.x;
    const int n0 = blockIdx.x * 64, k0 = blockIdx.y * 64;
#pragma unroll
    for (int i = 0; i < 4; i++) {
        int idx = tid + i * 256;
        int r = idx >> 4, c4 = idx & 15;
        *(float4*)&T[r][c4 * 4] = *(const float4*)&in[(size_t)(k0 + r) * N + n0 + c4 * 4];
    }
    __syncthreads();
#pragma unroll
    for (int i = 0; i < 4; i++) {
        int idx = tid + i * 256;
        int n = idx >> 4, kg = idx & 15;
        bf16x4 h, l;
#pragma unroll
        for (int j = 0; j < 4; j++) {
            short2 s = split2(T[kg * 4 + j][n]);
            h[j] = s.x; l[j] = s.y;
        }
        *(bf16x4*)&hiT[(size_t)(n0 + n) * K + k0 + kg * 4] = h;
        *(bf16x4*)&loT[(size_t)(n0 + n) * K + k0 + kg * 4] = l;
    }
}

// ---------------- transpose V section of qkv -> vT[b][h][d][s]  (bf16)
__global__ __launch_bounds__(256) void transpose_v(
    const short* __restrict__ qkv, short* __restrict__ vT)
{
    __shared__ short T[64 * 68];   // [s][d], stride 68 shorts
    const int tid = threadIdx.x;
    const int bid = blockIdx.x;
    const int st = bid & 31, h = (bid >> 5) & 15, b = bid >> 9;
    const int s0 = st * 64;
    const short* src = qkv + (size_t)b * SLEN * (3 * DMODEL) + 2 * DMODEL + h * HDIM;

    const int srow = tid >> 3, sc8 = tid & 7;
#pragma unroll
    for (int it = 0; it < 2; it++) {
        int s = srow + it * 32;
        *(bf16x8*)&T[s * 68 + sc8 * 8] =
            *(const bf16x8*)&src[(size_t)(s0 + s) * (3 * DMODEL) + sc8 * 8];
    }
    __syncthreads();

    const int d = tid >> 2, sq = tid & 3;
    short* dst = vT + ((size_t)(b * NHEAD + h) * HDIM + d) * SLEN + s0 + sq * 16;
    bf16x8 o0, o1;
#pragma unroll
    for (int j = 0; j < 8; j++) {
        o0[j] = T[(sq * 16 + j) * 68 + d];
        o1[j] = T[(sq * 16 + 8 + j) * 68 + d];
    }
    *(bf16x8*)&dst[0] = o0;
    *(bf16x8*)&dst[8] = o1;
}

// ---------------- split-precision bf16 MFMA GEMM (unchanged)
#define GSTR 40

template<int OUT_BF16>
__global__ __launch_bounds__(256) void gemm_split(
    const short* __restrict__ Ahi, const short* __restrict__ Alo,
    const short* __restrict__ Bhi, const short* __restrict__ Blo,
    const float* __restrict__ bias, void* __restrict__ Cout,
    int M, int N, int K)
{
    __shared__ short AsH[128 * GSTR], AsL[128 * GSTR];
    __shared__ short BsH[128 * GSTR], BsL[128 * GSTR];

    const int tid  = threadIdx.x;
    const int wave = tid >> 6, lane = tid & 63;
    const int quad = lane >> 4, lr = lane & 15;
    const int wm = (wave >> 1) * 64, wn = (wave & 1) * 64;
    const int row0 = blockIdx.y * 128, col0 = blockIdx.x * 128;

    f32x4 acc[4][4];
#pragma unroll
    for (int i = 0; i < 4; i++)
#pragma unroll
        for (int j = 0; j < 4; j++) acc[i][j] = (f32x4){0.f, 0.f, 0.f, 0.f};

    const int sr = tid >> 2, sc = tid & 3;

    for (int k0 = 0; k0 < K; k0 += 32) {
        __syncthreads();
#pragma unroll
        for (int i = 0; i < 2; i++) {
            int rr = sr + i * 64;
            size_t ga = (size_t)(row0 + rr) * K + k0 + sc * 8;
            size_t gb = (size_t)(col0 + rr) * K + k0 + sc * 8;
            int ls = rr * GSTR + sc * 8;
            *(bf16x8*)&AsH[ls] = *(const bf16x8*)&Ahi[ga];
            *(bf16x8*)&AsL[ls] = *(const bf16x8*)&Alo[ga];
            *(bf16x8*)&BsH[ls] = *(const bf16x8*)&Bhi[gb];
            *(bf16x8*)&BsL[ls] = *(const bf16x8*)&Blo[gb];
        }
        __syncthreads();

        bf16x8 ah[4], al[4];
#pragma unroll
        for (int mt = 0; mt < 4; mt++) {
            int off = (wm + mt * 16 + lr) * GSTR + quad * 8;
            ah[mt] = *(const bf16x8*)&AsH[off];
            al[mt] = *(const bf16x8*)&AsL[off];
        }
#pragma unroll
        for (int nt = 0; nt < 4; nt++) {
            int off = (wn + nt * 16 + lr) * GSTR + quad * 8;
            bf16x8 bh = *(const bf16x8*)&BsH[off];
            bf16x8 bl = *(const bf16x8*)&BsL[off];
#pragma unroll
            for (int mt = 0; mt < 4; mt++) {
                acc[mt][nt] = __builtin_amdgcn_mfma_f32_16x16x32_bf16(ah[mt], bh, acc[mt][nt], 0, 0, 0);
                acc[mt][nt] = __builtin_amdgcn_mfma_f32_16x16x32_bf16(al[mt], bh, acc[mt][nt], 0, 0, 0);
                acc[mt][nt] = __builtin_amdgcn_mfma_f32_16x16x32_bf16(ah[mt], bl, acc[mt][nt], 0, 0, 0);
            }
        }
    }

#pragma unroll
    for (int mt = 0; mt < 4; mt++) {
#pragma unroll
        for (int nt = 0; nt < 4; nt++) {
            int col = col0 + wn + nt * 16 + lr;
            float bv = bias[col];
#pragma unroll
            for (int r = 0; r < 4; r++) {
                int row = row0 + wm + mt * 16 + quad * 4 + r;
                float v = acc[mt][nt][r] + bv;
                if (OUT_BF16)
                    ((short*)Cout)[(size_t)row * N + col] = f2bf(v);
                else
                    ((float*)Cout)[(size_t)row * N + col] = v;
            }
        }
    }
}

// ---------------- fused attention v5: 16x16x16 layout-chaining,
// pre-transposed V (vector staging both tiles), stride-76 conflict-free LDS,
// Q pre-scaled (no per-exp mul), row-sum via ones-MFMA (no adds/shuffles).
#define ASTR 76   // LDS row stride (shorts): 38 dwords; 6*lr mod 32 distinct -> 2-way max
#define NT   (SLEN / 64)
#define QK_SCALE_LOG2E 0.1803368801111244f   // 0.125 * log2(e)

__global__ __launch_bounds__(256) void attn_mfma(
    const short* __restrict__ qkv, const short* __restrict__ vT,
    short* __restrict__ ohi, short* __restrict__ olo)
{
    __shared__ short Ks[2][64 * ASTR];   // K tile, row-major [k][d]
    __shared__ short Vt[2][64 * ASTR];   // V^T tile [d][k]

    const int tid  = threadIdx.x;
    const int lane = tid & 63;
    const int wave = tid >> 6;
    const int quad = lane >> 4;
    const int lr   = lane & 15;
    const int wq0  = wave * 16;

    const int bid = blockIdx.x;
    const int qt = bid & 31;
    const int h  = (bid >> 5) & 15;
    const int b  = bid >> 9;
    const int q0 = qt * 64;

    const short* qbase = qkv + (size_t)b * SLEN * (3 * DMODEL) + h * HDIM;
    const short* kbase = qbase + DMODEL;
    const short* vtbase = vT + (size_t)(b * NHEAD + h) * HDIM * SLEN;

    // Q as B-fragments, pre-scaled by 0.125*log2(e): B[d = ds*16+quad*4+j][q = lr]
    bf16x4 qf[4];
#pragma unroll
    for (int ds = 0; ds < 4; ds++) {
        bf16x4 q = *(const bf16x4*)&qbase[(size_t)(q0 + wq0 + lr) * (3 * DMODEL) + ds * 16 + quad * 4];
#pragma unroll
        for (int j = 0; j < 4; j++)
            q[j] = f2bf(bf2f(q[j]) * QK_SCALE_LOG2E);
        qf[ds] = q;
    }

    // ones A-fragment for the row-sum MFMA
    bf16x4 ones;
#pragma unroll
    for (int j = 0; j < 4; j++) ones[j] = (short)0x3F80;

    f32x4 oacc[4];   // O^T tiles: D[d = dt*16 + quad*4 + r][q = lr]
#pragma unroll
    for (int t = 0; t < 4; t++) oacc[t] = (f32x4){0.f, 0.f, 0.f, 0.f};
    f32x4 sacc = {0.f, 0.f, 0.f, 0.f};   // every entry -> full denominator for q=lr

    // staging mapping (identical for K and V^T): row = tid>>3 (+32), chunk = tid&7
    const int srow = tid >> 3, sc8 = tid & 7;

    bf16x8 kpre[2], vpre[2];
#pragma unroll
    for (int it = 0; it < 2; it++) {
        int r = srow + it * 32;
        kpre[it] = *(const bf16x8*)&kbase[(size_t)r * (3 * DMODEL) + sc8 * 8];
        vpre[it] = *(const bf16x8*)&vtbase[(size_t)r * SLEN + sc8 * 8];
    }

    for (int kt = 0; kt < NT; kt++) {
        const int cur = kt & 1;
        short* ks = Ks[cur];
        short* vt = Vt[cur];

        // write tile kt (in regs) to LDS buffer `cur` — 4x b128, ~2-way banks
#pragma unroll
        for (int it = 0; it < 2; it++) {
            *(bf16x8*)&ks[(srow + it * 32) * ASTR + sc8 * 8] = kpre[it];
            *(bf16x8*)&vt[(srow + it * 32) * ASTR + sc8 * 8] = vpre[it];
        }

        // issue global loads for tile kt+1 (latency spans barrier + compute)
        if (kt + 1 < NT) {
            const int k0 = (kt + 1) * 64;
#pragma unroll
            for (int it = 0; it < 2; it++) {
                int r = srow + it * 32;
                kpre[it] = *(const bf16x8*)&kbase[(size_t)(k0 + r) * (3 * DMODEL) + sc8 * 8];
                vpre[it] = *(const bf16x8*)&vtbase[(size_t)r * SLEN + k0 + sc8 * 8];
            }
        }

        __syncthreads();   // buffer `cur` complete; reads of 1-cur finished pre-barrier

        // per 16-key tile: S^T = K·Q^T, exp2, O^T += V^T·P^T, sacc += 1·P^T
#pragma unroll
        for (int ct = 0; ct < 4; ct++) {
            f32x4 st = {0.f, 0.f, 0.f, 0.f};
#pragma unroll
            for (int ds = 0; ds < 4; ds++) {
                bf16x4 kf = *(const bf16x4*)&ks[(ct * 16 + lr) * ASTR + ds * 16 + quad * 4];
                st = __builtin_amdgcn_mfma_f32_16x16x16bf16_1k(kf, qf[ds], st, 0, 0, 0);
            }
            float p[4];
#pragma unroll
            for (int r = 0; r < 4; r++) p[r] = exp2f(st[r]);
            // pack to bf16 by truncation: one v_perm per pair
            union { uint2 u; bf16x4 v; } pk;
            pk.u.x = __builtin_amdgcn_perm(fbits(p[1]), fbits(p[0]), 0x07060302u);
            pk.u.y = __builtin_amdgcn_perm(fbits(p[3]), fbits(p[2]), 0x07060302u);
            bf16x4 pf = pk.v;
            sacc = __builtin_amdgcn_mfma_f32_16x16x16bf16_1k(ones, pf, sacc, 0, 0, 0);
#pragma unroll
            for (int dt = 0; dt < 4; dt++) {
                bf16x4 vf = *(const bf16x4*)&vt[(dt * 16 + lr) * ASTR + ct * 16 + quad * 4];
                oacc[dt] = __builtin_amdgcn_mfma_f32_16x16x16bf16_1k(vf, pf, oacc[dt], 0, 0, 0);
            }
        }
    }

    const float inv = 1.0f / sacc[0];   // full sum over all keys (MFMA-reduced)

    // write O: lane holds O^T[d = dt*16+quad*4+r][q = lr] -> 4 consecutive cols
    const int row = b * SLEN + q0 + wq0 + lr;
#pragma unroll
    for (int dt = 0; dt < 4; dt++) {
        bf16x4 h4, l4;
#pragma unroll
        for (int r = 0; r < 4; r++) {
            float o = oacc[dt][r] * inv;
            short2 s2 = split2(o);
            h4[r] = s2.x; l4[r] = s2.y;
        }
        int col = h * HDIM + dt * 16 + quad * 4;
        *(bf16x4*)&ohi[(size_t)row * DMODEL + col] = h4;
        *(bf16x4*)&olo[(size_t)row * DMODEL + col] = l4;
    }
}

extern "C" void kernel_launch(void* const* d_in, const int* in_sizes, int n_in,
                              void* d_out, int out_size, void* d_ws, size_t ws_size,
                              hipStream_t stream) {
    (void)in_sizes; (void)n_in; (void)out_size; (void)ws_size;
    const float* x     = (const float*)d_in[0];
    const float* Wqkv  = (const float*)d_in[1];
    const float* bqkv  = (const float*)d_in[2];
    const float* Wproj = (const float*)d_in[3];
    const float* bproj = (const float*)d_in[4];
    float* out = (float*)d_out;

    // workspace layout (shorts), peak 58.8 MB
    short* qkv  = (short*)d_ws;                         // 4096*3072
    short* xhi  = qkv + (size_t)MROWS * 3 * DMODEL;     // 4096*1024
    short* xlo  = xhi + (size_t)MROWS * DMODEL;
    short* wqhi = xlo + (size_t)MROWS * DMODEL;         // 3072*1024 (W_qkv^T)
    short* wqlo = wqhi + (size_t)3 * DMODEL * DMODEL;
    short* wphi = wqlo + (size_t)3 * DMODEL * DMODEL;   // 1024*1024 (W_proj^T)
    short* wplo = wphi + (size_t)DMODEL * DMODEL;
    short* ahi  = xhi;   // reuse x region after QKV GEMM
    short* alo  = xlo;
    short* vT   = wqhi;  // reuse W_qkv^T region after QKV GEMM (4096*1024 <= 2*3072*1024)

    // prep: split x; split+transpose weights
    split_2d<<<dim3(MROWS * DMODEL / 4 / 256), 256, 0, stream>>>(x, xhi, xlo, MROWS * DMODEL / 4);
    split_transpose<<<dim3(3 * DMODEL / 64, DMODEL / 64), 256, 0, stream>>>(Wqkv, wqhi, wqlo, DMODEL, 3 * DMODEL);
    split_transpose<<<dim3(DMODEL / 64, DMODEL / 64), 256, 0, stream>>>(Wproj, wphi, wplo, DMODEL, DMODEL);

    // 1) qkv(bf16) = x @ W_qkv + b_qkv
    gemm_split<1><<<dim3(3 * DMODEL / 128, MROWS / 128), 256, 0, stream>>>(
        xhi, xlo, wqhi, wqlo, bqkv, (void*)qkv, MROWS, 3 * DMODEL, DMODEL);

    // 1b) transpose V section -> vT[b][h][d][s]  (overwrites dead W_qkv^T region)
    transpose_v<<<dim3(BATCH * NHEAD * (SLEN / 64)), 256, 0, stream>>>(qkv, vT);

    // 2) fused attention: bf16 qkv + vT -> attn (hi, lo)
    attn_mfma<<<dim3(BATCH * NHEAD * (SLEN / 64)), 256, 0, stream>>>(qkv, vT, ahi, alo);

    // 3) out(fp32) = attn @ W_proj + b_proj
    gemm_split<0><<<dim3(DMODEL / 128, MROWS / 128), 256, 0, stream>>>(
        ahi, alo, wphi, wplo, bproj, (void*)out, MROWS, DMODEL, DMODEL);
}

// Round 9
// 290.043 us; speedup vs baseline: 1.0774x; 1.0774x over previous
//
#include <hip/hip_runtime.h>

// Problem constants
#define BATCH 2
#define SLEN 2048
#define DMODEL 1024
#define NHEAD 16
#define HDIM 64
#define MROWS (BATCH * SLEN)   // 4096

typedef __attribute__((ext_vector_type(8))) short bf16x8;
typedef __attribute__((ext_vector_type(4))) short bf16x4;
typedef __attribute__((ext_vector_type(4))) float f32x4;
typedef __attribute__((ext_vector_type(8))) _Float16 f16x8;
typedef __attribute__((ext_vector_type(4))) _Float16 f16x4;

__device__ inline short f2bf(float x) {
    union { float f; unsigned u; } v; v.f = x;
    unsigned r = (v.u + 0x7FFFu + ((v.u >> 16) & 1u)) >> 16;
    return (short)r;
}
__device__ inline float bf2f(short h) {
    union { unsigned u; float f; } v; v.u = ((unsigned)(unsigned short)h) << 16;
    return v.f;
}
__device__ inline unsigned fbits(float x) {
    union { float f; unsigned u; } v; v.f = x; return v.u;
}

// ---------------- prep: split fp32 -> (hi, lo) fp16, same layout
__global__ __launch_bounds__(256) void split_2d_f16(
    const float* __restrict__ in, _Float16* __restrict__ hi, _Float16* __restrict__ lo, int n4)
{
    int i = blockIdx.x * 256 + threadIdx.x;
    if (i >= n4) return;
    float4 f = ((const float4*)in)[i];
    f16x4 h, l;
    float a[4] = {f.x, f.y, f.z, f.w};
#pragma unroll
    for (int j = 0; j < 4; j++) {
        _Float16 hh = (_Float16)a[j];
        h[j] = hh;
        l[j] = (_Float16)(a[j] - (float)hh);
    }
    ((f16x4*)hi)[i] = h;
    ((f16x4*)lo)[i] = l;
}

// ---------------- prep: transpose W[K][N] -> WT fp16 [N][K] (single precision)
__global__ __launch_bounds__(256) void transpose_f16(
    const float* __restrict__ in, _Float16* __restrict__ outT, int K, int N)
{
    __shared__ float T[64][68];
    const int tid = threadIdx.x;
    const int n0 = blockIdx.x * 64, k0 = blockIdx.y * 64;
#pragma unroll
    for (int i = 0; i < 4; i++) {
        int idx = tid + i * 256;
        int r = idx >> 4, c4 = idx & 15;
        *(float4*)&T[r][c4 * 4] = *(const float4*)&in[(size_t)(k0 + r) * N + n0 + c4 * 4];
    }
    __syncthreads();
#pragma unroll
    for (int i = 0; i < 4; i++) {
        int idx = tid + i * 256;
        int n = idx >> 4, kg = idx & 15;
        f16x4 h;
#pragma unroll
        for (int j = 0; j < 4; j++)
            h[j] = (_Float16)T[kg * 4 + j][n];
        *(f16x4*)&outT[(size_t)(n0 + n) * K + k0 + kg * 4] = h;
    }
}

// ---------------- transpose V section of qkv -> vT[b][h][d][s]  (bf16)
__global__ __launch_bounds__(256) void transpose_v(
    const short* __restrict__ qkv, short* __restrict__ vT)
{
    __shared__ short T[64 * 68];   // [s][d], stride 68 shorts
    const int tid = threadIdx.x;
    const int bid = blockIdx.x;
    const int st = bid & 31, h = (bid >> 5) & 15, b = bid >> 9;
    const int s0 = st * 64;
    const short* src = qkv + (size_t)b * SLEN * (3 * DMODEL) + 2 * DMODEL + h * HDIM;

    const int srow = tid >> 3, sc8 = tid & 7;
#pragma unroll
    for (int it = 0; it < 2; it++) {
        int s = srow + it * 32;
        *(bf16x8*)&T[s * 68 + sc8 * 8] =
            *(const bf16x8*)&src[(size_t)(s0 + s) * (3 * DMODEL) + sc8 * 8];
    }
    __syncthreads();

    const int d = tid >> 2, sq = tid & 3;
    short* dst = vT + ((size_t)(b * NHEAD + h) * HDIM + d) * SLEN + s0 + sq * 16;
    bf16x8 o0, o1;
#pragma unroll
    for (int j = 0; j < 8; j++) {
        o0[j] = T[(sq * 16 + j) * 68 + d];
        o1[j] = T[(sq * 16 + 8 + j) * 68 + d];
    }
    *(bf16x8*)&dst[0] = o0;
    *(bf16x8*)&dst[8] = o1;
}

// ---------------- split-precision fp16 MFMA GEMM, 2-pass (split A only)
// C[M,N] = (Ahi+Alo)[M,K] · B[K,N] + bias;  B given TRANSPOSED [N][K] fp16.
#define GSTR 40   // LDS row stride (f16 elems): 80 B, 16B-aligned, 2-way-free banks

template<int OUT_BF16>
__global__ __launch_bounds__(256) void gemm_split(
    const _Float16* __restrict__ Ahi, const _Float16* __restrict__ Alo,
    const _Float16* __restrict__ Bw,
    const float* __restrict__ bias, void* __restrict__ Cout,
    int M, int N, int K)
{
    __shared__ _Float16 AsH[128 * GSTR], AsL[128 * GSTR], Bs[128 * GSTR];

    const int tid  = threadIdx.x;
    const int wave = tid >> 6, lane = tid & 63;
    const int quad = lane >> 4, lr = lane & 15;
    const int wm = (wave >> 1) * 64, wn = (wave & 1) * 64;
    const int row0 = blockIdx.y * 128, col0 = blockIdx.x * 128;

    f32x4 acc[4][4];
#pragma unroll
    for (int i = 0; i < 4; i++)
#pragma unroll
        for (int j = 0; j < 4; j++) acc[i][j] = (f32x4){0.f, 0.f, 0.f, 0.f};

    const int sr = tid >> 2, sc = tid & 3;

    for (int k0 = 0; k0 < K; k0 += 32) {
        __syncthreads();
#pragma unroll
        for (int i = 0; i < 2; i++) {
            int rr = sr + i * 64;
            size_t ga = (size_t)(row0 + rr) * K + k0 + sc * 8;
            size_t gb = (size_t)(col0 + rr) * K + k0 + sc * 8;
            int ls = rr * GSTR + sc * 8;
            *(f16x8*)&AsH[ls] = *(const f16x8*)&Ahi[ga];
            *(f16x8*)&AsL[ls] = *(const f16x8*)&Alo[ga];
            *(f16x8*)&Bs[ls]  = *(const f16x8*)&Bw[gb];
        }
        __syncthreads();

        f16x8 ah[4], al[4];
#pragma unroll
        for (int mt = 0; mt < 4; mt++) {
            int off = (wm + mt * 16 + lr) * GSTR + quad * 8;
            ah[mt] = *(const f16x8*)&AsH[off];
            al[mt] = *(const f16x8*)&AsL[off];
        }
#pragma unroll
        for (int nt = 0; nt < 4; nt++) {
            int off = (wn + nt * 16 + lr) * GSTR + quad * 8;
            f16x8 b = *(const f16x8*)&Bs[off];
#pragma unroll
            for (int mt = 0; mt < 4; mt++) {
                acc[mt][nt] = __builtin_amdgcn_mfma_f32_16x16x32_f16(ah[mt], b, acc[mt][nt], 0, 0, 0);
                acc[mt][nt] = __builtin_amdgcn_mfma_f32_16x16x32_f16(al[mt], b, acc[mt][nt], 0, 0, 0);
            }
        }
    }

    // epilogue: D[m = quad*4 + r][n = lr]
#pragma unroll
    for (int mt = 0; mt < 4; mt++) {
#pragma unroll
        for (int nt = 0; nt < 4; nt++) {
            int col = col0 + wn + nt * 16 + lr;
            float bv = bias[col];
#pragma unroll
            for (int r = 0; r < 4; r++) {
                int row = row0 + wm + mt * 16 + quad * 4 + r;
                float v = acc[mt][nt][r] + bv;
                if (OUT_BF16)
                    ((short*)Cout)[(size_t)row * N + col] = f2bf(v);
                else
                    ((float*)Cout)[(size_t)row * N + col] = v;
            }
        }
    }
}

// ---------------- fused attention v5 (unchanged math, fp16 hi/lo epilogue)
#define ASTR 76   // LDS row stride (shorts): 2-way max bank aliasing
#define NT   (SLEN / 64)
#define QK_SCALE_LOG2E 0.1803368801111244f   // 0.125 * log2(e)

__global__ __launch_bounds__(256) void attn_mfma(
    const short* __restrict__ qkv, const short* __restrict__ vT,
    _Float16* __restrict__ ohi, _Float16* __restrict__ olo)
{
    __shared__ short Ks[2][64 * ASTR];   // K tile, row-major [k][d]
    __shared__ short Vt[2][64 * ASTR];   // V^T tile [d][k]

    const int tid  = threadIdx.x;
    const int lane = tid & 63;
    const int wave = tid >> 6;
    const int quad = lane >> 4;
    const int lr   = lane & 15;
    const int wq0  = wave * 16;

    const int bid = blockIdx.x;
    const int qt = bid & 31;
    const int h  = (bid >> 5) & 15;
    const int b  = bid >> 9;
    const int q0 = qt * 64;

    const short* qbase = qkv + (size_t)b * SLEN * (3 * DMODEL) + h * HDIM;
    const short* kbase = qbase + DMODEL;
    const short* vtbase = vT + (size_t)(b * NHEAD + h) * HDIM * SLEN;

    // Q as B-fragments, pre-scaled by 0.125*log2(e): B[d = ds*16+quad*4+j][q = lr]
    bf16x4 qf[4];
#pragma unroll
    for (int ds = 0; ds < 4; ds++) {
        bf16x4 q = *(const bf16x4*)&qbase[(size_t)(q0 + wq0 + lr) * (3 * DMODEL) + ds * 16 + quad * 4];
#pragma unroll
        for (int j = 0; j < 4; j++)
            q[j] = f2bf(bf2f(q[j]) * QK_SCALE_LOG2E);
        qf[ds] = q;
    }

    // ones A-fragment for the row-sum MFMA
    bf16x4 ones;
#pragma unroll
    for (int j = 0; j < 4; j++) ones[j] = (short)0x3F80;

    f32x4 oacc[4];   // O^T tiles: D[d = dt*16 + quad*4 + r][q = lr]
#pragma unroll
    for (int t = 0; t < 4; t++) oacc[t] = (f32x4){0.f, 0.f, 0.f, 0.f};
    f32x4 sacc = {0.f, 0.f, 0.f, 0.f};

    const int srow = tid >> 3, sc8 = tid & 7;

    bf16x8 kpre[2], vpre[2];
#pragma unroll
    for (int it = 0; it < 2; it++) {
        int r = srow + it * 32;
        kpre[it] = *(const bf16x8*)&kbase[(size_t)r * (3 * DMODEL) + sc8 * 8];
        vpre[it] = *(const bf16x8*)&vtbase[(size_t)r * SLEN + sc8 * 8];
    }

    for (int kt = 0; kt < NT; kt++) {
        const int cur = kt & 1;
        short* ks = Ks[cur];
        short* vt = Vt[cur];

#pragma unroll
        for (int it = 0; it < 2; it++) {
            *(bf16x8*)&ks[(srow + it * 32) * ASTR + sc8 * 8] = kpre[it];
            *(bf16x8*)&vt[(srow + it * 32) * ASTR + sc8 * 8] = vpre[it];
        }

        if (kt + 1 < NT) {
            const int k0 = (kt + 1) * 64;
#pragma unroll
            for (int it = 0; it < 2; it++) {
                int r = srow + it * 32;
                kpre[it] = *(const bf16x8*)&kbase[(size_t)(k0 + r) * (3 * DMODEL) + sc8 * 8];
                vpre[it] = *(const bf16x8*)&vtbase[(size_t)r * SLEN + k0 + sc8 * 8];
            }
        }

        __syncthreads();

#pragma unroll
        for (int ct = 0; ct < 4; ct++) {
            f32x4 st = {0.f, 0.f, 0.f, 0.f};
#pragma unroll
            for (int ds = 0; ds < 4; ds++) {
                bf16x4 kf = *(const bf16x4*)&ks[(ct * 16 + lr) * ASTR + ds * 16 + quad * 4];
                st = __builtin_amdgcn_mfma_f32_16x16x16bf16_1k(kf, qf[ds], st, 0, 0, 0);
            }
            float p[4];
#pragma unroll
            for (int r = 0; r < 4; r++) p[r] = exp2f(st[r]);
            union { uint2 u; bf16x4 v; } pk;
            pk.u.x = __builtin_amdgcn_perm(fbits(p[1]), fbits(p[0]), 0x07060302u);
            pk.u.y = __builtin_amdgcn_perm(fbits(p[3]), fbits(p[2]), 0x07060302u);
            bf16x4 pf = pk.v;
            sacc = __builtin_amdgcn_mfma_f32_16x16x16bf16_1k(ones, pf, sacc, 0, 0, 0);
#pragma unroll
            for (int dt = 0; dt < 4; dt++) {
                bf16x4 vf = *(const bf16x4*)&vt[(dt * 16 + lr) * ASTR + ct * 16 + quad * 4];
                oacc[dt] = __builtin_amdgcn_mfma_f32_16x16x16bf16_1k(vf, pf, oacc[dt], 0, 0, 0);
            }
        }
    }

    const float inv = 1.0f / sacc[0];

    // write O as fp16 hi/lo (exact to 2^-22) for the split proj GEMM
    const int row = b * SLEN + q0 + wq0 + lr;
#pragma unroll
    for (int dt = 0; dt < 4; dt++) {
        f16x4 h4, l4;
#pragma unroll
        for (int r = 0; r < 4; r++) {
            float o = oacc[dt][r] * inv;
            _Float16 hh = (_Float16)o;
            h4[r] = hh;
            l4[r] = (_Float16)(o - (float)hh);
        }
        int col = h * HDIM + dt * 16 + quad * 4;
        *(f16x4*)&ohi[(size_t)row * DMODEL + col] = h4;
        *(f16x4*)&olo[(size_t)row * DMODEL + col] = l4;
    }
}

extern "C" void kernel_launch(void* const* d_in, const int* in_sizes, int n_in,
                              void* d_out, int out_size, void* d_ws, size_t ws_size,
                              hipStream_t stream) {
    (void)in_sizes; (void)n_in; (void)out_size; (void)ws_size;
    const float* x     = (const float*)d_in[0];
    const float* Wqkv  = (const float*)d_in[1];
    const float* bqkv  = (const float*)d_in[2];
    const float* Wproj = (const float*)d_in[3];
    const float* bproj = (const float*)d_in[4];
    float* out = (float*)d_out;

    // workspace layout (2-byte units), peak 58.7 MB
    short* qkv = (short*)d_ws;                               // 4096*3072 bf16
    _Float16* xhi = (_Float16*)(qkv + (size_t)MROWS * 3 * DMODEL);  // 4096*1024 f16
    _Float16* xlo = xhi + (size_t)MROWS * DMODEL;
    _Float16* wq  = xlo + (size_t)MROWS * DMODEL;            // 3072*1024 f16 (W_qkv^T)
    _Float16* wp  = wq + (size_t)3 * DMODEL * DMODEL;        // 1024*1024 f16 (W_proj^T)
    short* vT = (short*)(wp + (size_t)DMODEL * DMODEL);      // 4096*1024 bf16
    _Float16* ahi = xhi;   // reuse x region after QKV GEMM
    _Float16* alo = xlo;

    // prep: split x (fp16 hi/lo); transpose weights to fp16
    split_2d_f16<<<dim3(MROWS * DMODEL / 4 / 256), 256, 0, stream>>>(x, xhi, xlo, MROWS * DMODEL / 4);
    transpose_f16<<<dim3(3 * DMODEL / 64, DMODEL / 64), 256, 0, stream>>>(Wqkv, wq, DMODEL, 3 * DMODEL);
    transpose_f16<<<dim3(DMODEL / 64, DMODEL / 64), 256, 0, stream>>>(Wproj, wp, DMODEL, DMODEL);

    // 1) qkv(bf16) = x @ W_qkv + b_qkv   (fp16 2-pass split-A)
    gemm_split<1><<<dim3(3 * DMODEL / 128, MROWS / 128), 256, 0, stream>>>(
        xhi, xlo, wq, bqkv, (void*)qkv, MROWS, 3 * DMODEL, DMODEL);

    // 1b) transpose V section -> vT[b][h][d][s]
    transpose_v<<<dim3(BATCH * NHEAD * (SLEN / 64)), 256, 0, stream>>>(qkv, vT);

    // 2) fused attention: bf16 qkv + vT -> attn (fp16 hi/lo)
    attn_mfma<<<dim3(BATCH * NHEAD * (SLEN / 64)), 256, 0, stream>>>(qkv, vT, ahi, alo);

    // 3) out(fp32) = attn @ W_proj + b_proj   (fp16 2-pass split-A)
    gemm_split<0><<<dim3(DMODEL / 128, MROWS / 128), 256, 0, stream>>>(
        ahi, alo, wp, bproj, (void*)out, MROWS, DMODEL, DMODEL);
}